// Round 1
// 8254.062 us; speedup vs baseline: 2.3323x; 2.3323x over previous
//
#include <hip/hip_runtime.h>
#include <math.h>

// Problem constants
constexpr int L = 4, B = 4, T = 2048, C = 1024, H = 16, F = 4096, V = 32000;
constexpr int D = C / H;        // 64
constexpr int M = B * T;        // 8192
constexpr int C3 = 3 * C;       // fused QKV width
constexpr float EPS = 1e-5f;

typedef __bf16 bf16_t;
typedef __bf16 bf16x8 __attribute__((ext_vector_type(8)));
typedef __bf16 bf16x4 __attribute__((ext_vector_type(4)));
typedef float  f32x4  __attribute__((ext_vector_type(4)));

#define GLOBAL_AS(p) ((const __attribute__((address_space(1))) void*)(p))
#define LDS_AS(p)    ((__attribute__((address_space(3))) void*)(p))

// ---------------------------------------------------------------------------
// Embedding: x[b,t,:] = tok_emb[idx[b,t],:] + pos_emb[t,:]  (fp32 residual)
// ---------------------------------------------------------------------------
__global__ __launch_bounds__(256) void embed_kernel(
    const int* __restrict__ idx, const float* __restrict__ tok,
    const float* __restrict__ pos, float* __restrict__ x) {
  size_t e4 = ((size_t)blockIdx.x * 256 + threadIdx.x) * 4;
  int row = (int)(e4 / C);
  int c   = (int)(e4 % C);
  int t   = row % T;
  int tokid = idx[row];
  const float4 tv = *(const float4*)(tok + (size_t)tokid * C + c);
  const float4 pv = *(const float4*)(pos + (size_t)t * C + c);
  float4 o;
  o.x = tv.x + pv.x; o.y = tv.y + pv.y; o.z = tv.z + pv.z; o.w = tv.w + pv.w;
  *(float4*)(x + e4) = o;
}

// ---------------------------------------------------------------------------
// LayerNorm (fp32 in). OutT = __bf16 (GEMM A-operand) or float (final LN).
// one 256-thread block per row; in-row = bid*rowMul + rowAdd; out-row = bid.
// ---------------------------------------------------------------------------
template <typename OutT>
__global__ __launch_bounds__(256) void ln_kernel(
    const float* __restrict__ xin, const float* __restrict__ g,
    const float* __restrict__ bta, OutT* __restrict__ out,
    int rowMul, int rowAdd) {
  int row_in = blockIdx.x * rowMul + rowAdd;
  const float* xr = xin + (size_t)row_in * C;
  int c = threadIdx.x * 4;
  float4 xv = *(const float4*)(xr + c);
  float s  = xv.x + xv.y + xv.z + xv.w;
  float ss = xv.x * xv.x + xv.y * xv.y + xv.z * xv.z + xv.w * xv.w;
  #pragma unroll
  for (int off = 32; off > 0; off >>= 1) {
    s  += __shfl_xor(s, off);
    ss += __shfl_xor(ss, off);
  }
  __shared__ float sh[8];
  int wid = threadIdx.x >> 6, lane = threadIdx.x & 63;
  if (lane == 0) { sh[wid * 2] = s; sh[wid * 2 + 1] = ss; }
  __syncthreads();
  s  = sh[0] + sh[2] + sh[4] + sh[6];
  ss = sh[1] + sh[3] + sh[5] + sh[7];
  float mean = s / C;
  float var  = ss / C - mean * mean;
  float inv  = rsqrtf(var + EPS);
  float4 gv = *(const float4*)(g + c);
  float4 bv = *(const float4*)(bta + c);
  float o0 = (xv.x - mean) * inv * gv.x + bv.x;
  float o1 = (xv.y - mean) * inv * gv.y + bv.y;
  float o2 = (xv.z - mean) * inv * gv.z + bv.z;
  float o3 = (xv.w - mean) * inv * gv.w + bv.w;
  if constexpr (sizeof(OutT) == 2) {
    bf16x4 ov;
    ov[0] = (__bf16)o0; ov[1] = (__bf16)o1; ov[2] = (__bf16)o2; ov[3] = (__bf16)o3;
    *(bf16x4*)(out + (size_t)blockIdx.x * C + c) = ov;
  } else {
    float4 o; o.x = o0; o.y = o1; o.z = o2; o.w = o3;
    *(float4*)(out + (size_t)blockIdx.x * C + c) = o;
  }
}

// ---------------------------------------------------------------------------
// Weight convert+transpose: W[K][N] fp32 -> Wt[N][K] bf16 (per-layer via z).
// ---------------------------------------------------------------------------
__global__ __launch_bounds__(256) void convw_kernel(
    const float* __restrict__ W, bf16_t* __restrict__ Wt,
    int K, int N, size_t dstL) {
  const size_t soff = (size_t)blockIdx.z * K * N;
  const size_t doff = (size_t)blockIdx.z * dstL;
  __shared__ float s[32][33];
  int n0 = blockIdx.x * 32, k0 = blockIdx.y * 32;
  int tx = threadIdx.x & 31, ty = threadIdx.x >> 5;  // 32 x 8
  #pragma unroll
  for (int i = 0; i < 4; ++i)
    s[ty + i * 8][tx] = W[soff + (size_t)(k0 + ty + i * 8) * N + n0 + tx];
  __syncthreads();
  #pragma unroll
  for (int i = 0; i < 4; ++i)
    Wt[doff + (size_t)(n0 + ty + i * 8) * K + k0 + tx] = (__bf16)s[tx][ty + i * 8];
}

// Pack bq|bk|bv -> bqkv[L][3C]
__global__ __launch_bounds__(256) void packb_kernel(
    const float* __restrict__ bq, const float* __restrict__ bk,
    const float* __restrict__ bv, float* __restrict__ bqkv) {
  int i = blockIdx.x * 256 + threadIdx.x;       // < L*3C
  int l = i / C3, r = i % C3, sec = r / C, c = r % C;
  const float* src = (sec == 0) ? bq : (sec == 1) ? bk : bv;
  bqkv[i] = src[l * C + c];
}

// ---------------------------------------------------------------------------
// bf16 MFMA GEMM: Cout[M x N] = A[M x K](bf16) @ Bt[N x K](bf16) + bias
//                 (+resid fp32) (relu?)  -> OutT (fp32 or bf16)
// 128x128 tile, BK=64, 4 waves (2x2), 4x4 16x16x32 frags per wave.
// Staging: global_load_lds 16B, linear LDS dest, inverse-swizzled source;
// ds_read_b128 with b ^= (row&7)<<4  (bank-conflict-free fragment reads).
// ---------------------------------------------------------------------------
template <typename OutT>
__global__ __launch_bounds__(256) void gemm_bf16_kernel(
    const bf16_t* __restrict__ A, const bf16_t* __restrict__ Bt,
    const float* __restrict__ bias, const float* resid,
    OutT* Cout, int N, int K, int relu) {
  constexpr int BK = 64;                 // k per LDS tile; row = 128 B
  __shared__ bf16_t sA[128 * BK];        // [row(M)][k], swizzled within row
  __shared__ bf16_t sB[128 * BK];        // [row(N)][k]
  const int tid = threadIdx.x;
  const int row0 = blockIdx.x * 128;     // M
  const int col0 = blockIdx.y * 128;     // N
  const int wv = tid >> 6, l = tid & 63;
  const int wm = wv >> 1, wn = wv & 1;

  // staging map: inst i stages rows i*32 + (tid>>3); 16B chunk tid&7
  const int sr  = tid >> 3;
  const int seg = tid & 7;
  const int ssw = (seg ^ (sr & 7)) * 8;  // inverse-swizzled src elem offset

  // fragment read map
  const int lc = l & 15, lg = l >> 4;
  const int sw = (l & 7) << 4;           // read-side XOR swizzle (row&7)<<4

  f32x4 acc[4][4] = {};

  for (int k0 = 0; k0 < K; k0 += BK) {
    __syncthreads();   // previous tile fully consumed
    #pragma unroll
    for (int i = 0; i < 4; ++i) {
      const bf16_t* ga = A  + (size_t)(row0 + i * 32 + sr) * K + k0 + ssw;
      const bf16_t* gb = Bt + (size_t)(col0 + i * 32 + sr) * K + k0 + ssw;
      __builtin_amdgcn_global_load_lds(GLOBAL_AS(ga),
          LDS_AS((char*)sA + i * 4096 + wv * 1024), 16, 0, 0);
      __builtin_amdgcn_global_load_lds(GLOBAL_AS(gb),
          LDS_AS((char*)sB + i * 4096 + wv * 1024), 16, 0, 0);
    }
    __syncthreads();   // vmcnt(0) drain + barrier: tile ready
    #pragma unroll
    for (int ks = 0; ks < 2; ++ks) {
      const int bco = ks * 64 + lg * 16;       // logical byte-in-row
      const int bph = bco ^ sw;                // physical (swizzled)
      bf16x8 af[4], bfr[4];
      #pragma unroll
      for (int i = 0; i < 4; ++i) {
        af[i]  = *(const bf16x8*)((const char*)sA +
                   (size_t)((wm * 64 + i * 16 + lc) * 128 + bph));
        bfr[i] = *(const bf16x8*)((const char*)sB +
                   (size_t)((wn * 64 + i * 16 + lc) * 128 + bph));
      }
      #pragma unroll
      for (int i = 0; i < 4; ++i)
        #pragma unroll
        for (int j = 0; j < 4; ++j)
          acc[i][j] = __builtin_amdgcn_mfma_f32_16x16x32_bf16(
              af[i], bfr[j], acc[i][j], 0, 0, 0);
    }
  }

  // epilogue: D col = lane&15, row = (lane>>4)*4 + reg
  float bsv[4];
  #pragma unroll
  for (int j = 0; j < 4; ++j) bsv[j] = bias[col0 + wn * 64 + j * 16 + lc];
  #pragma unroll
  for (int i = 0; i < 4; ++i) {
    #pragma unroll
    for (int r = 0; r < 4; ++r) {
      int rr = row0 + wm * 64 + i * 16 + lg * 4 + r;
      const float* resrow = resid ? resid + (size_t)rr * N : nullptr;
      #pragma unroll
      for (int j = 0; j < 4; ++j) {
        int cc = col0 + wn * 64 + j * 16 + lc;
        float v = acc[i][j][r] + bsv[j];
        if (relu) v = fmaxf(v, 0.f);
        if (resrow) v += resrow[cc];
        Cout[(size_t)rr * N + cc] = (OutT)v;
      }
    }
  }
}

// ---------------------------------------------------------------------------
// Flash attention, fp32 math, bf16 I/O. 4 lanes per query (16 of D each),
// 64 queries per 256-thread block; grid (M/64, H). K/V tiles: bf16 global ->
// fp32 LDS (converted once, reused by 64 queries). Dot reduced via shfl_xor.
// Writes attention output as bf16 into hb (A-operand of the Wo GEMM).
// ---------------------------------------------------------------------------
__global__ __launch_bounds__(256) void flash_attn_kernel(
    const bf16_t* __restrict__ qkv, bf16_t* __restrict__ out) {
  const int h   = blockIdx.y;
  const int tid = threadIdx.x;
  const int g   = tid & 3;                 // lane-in-query: owns dims g*16..+15
  const int ql  = tid >> 2;                // query 0..63
  const int row = blockIdx.x * 64 + ql;    // global token row
  const int b   = row / T, t = row % T;
  const int t0  = (blockIdx.x * 64) % T;

  __shared__ float sK[64][68];
  __shared__ float sV[64][68];

  // q -> regs, pre-scaled by 1/sqrt(D)
  float q[16];
  {
    const bf16_t* qp = qkv + (size_t)row * C3 + h * D + g * 16;
    bf16x8 q1 = *(const bf16x8*)qp, q2 = *(const bf16x8*)(qp + 8);
    #pragma unroll
    for (int e = 0; e < 8; ++e) {
      q[e]     = (float)q1[e] * 0.125f;
      q[e + 8] = (float)q2[e] * 0.125f;
    }
  }

  float4 av[4] = {};
  float m = -1e30f, lsum = 0.f;

  const int r   = tid >> 2;                // staging row (== ql)
  const int c16 = g * 16;                  // staging col chunk
  const size_t kbase = (size_t)(b * T) * C3 + C + h * D;
  const size_t vbase = kbase + C;
  const int tmax = t0 + 63;

  for (int k0 = 0; k0 <= tmax; k0 += 64) {
    // issue global loads early (overlap previous tile's compute)
    const bf16_t* kg = qkv + kbase + (size_t)(k0 + r) * C3 + c16;
    const bf16_t* vg = qkv + vbase + (size_t)(k0 + r) * C3 + c16;
    bf16x8 k1 = *(const bf16x8*)kg, k2 = *(const bf16x8*)(kg + 8);
    bf16x8 v1 = *(const bf16x8*)vg, v2 = *(const bf16x8*)(vg + 8);
    __syncthreads();                        // prev tile consumed
    #pragma unroll
    for (int e = 0; e < 8; ++e) {
      sK[r][c16 + e]     = (float)k1[e];
      sK[r][c16 + 8 + e] = (float)k2[e];
      sV[r][c16 + e]     = (float)v1[e];
      sV[r][c16 + 8 + e] = (float)v2[e];
    }
    __syncthreads();                        // tile ready

    int lim = t - k0 + 1;
    if (lim > 64) lim = 64;
    for (int kk = 0; kk < lim; ++kk) {
      const float4* kr = (const float4*)&sK[kk][c16];
      float4 k0v = kr[0], k1v = kr[1], k2v = kr[2], k3v = kr[3];
      float s = q[0]  * k0v.x + q[1]  * k0v.y + q[2]  * k0v.z + q[3]  * k0v.w
              + q[4]  * k1v.x + q[5]  * k1v.y + q[6]  * k1v.z + q[7]  * k1v.w
              + q[8]  * k2v.x + q[9]  * k2v.y + q[10] * k2v.z + q[11] * k2v.w
              + q[12] * k3v.x + q[13] * k3v.y + q[14] * k3v.z + q[15] * k3v.w;
      s += __shfl_xor(s, 1);
      s += __shfl_xor(s, 2);               // all 4 lanes now hold full dot
      float mn   = fmaxf(m, s);
      float corr = __expf(m - mn);
      float p    = __expf(s - mn);
      lsum = lsum * corr + p;
      m = mn;
      const float4* vr = (const float4*)&sV[kk][c16];
      #pragma unroll
      for (int i = 0; i < 4; ++i) {
        float4 vv = vr[i];
        av[i].x = av[i].x * corr + p * vv.x;
        av[i].y = av[i].y * corr + p * vv.y;
        av[i].z = av[i].z * corr + p * vv.z;
        av[i].w = av[i].w * corr + p * vv.w;
      }
    }
  }

  const float inv = 1.f / lsum;
  bf16_t* orow = out + (size_t)row * C + h * D + g * 16;
  bf16x8 o1, o2;
  #pragma unroll
  for (int i = 0; i < 4; ++i) {
    float4 v = av[i];
    if (i < 2) {
      o1[i * 4 + 0] = (__bf16)(v.x * inv); o1[i * 4 + 1] = (__bf16)(v.y * inv);
      o1[i * 4 + 2] = (__bf16)(v.z * inv); o1[i * 4 + 3] = (__bf16)(v.w * inv);
    } else {
      o2[(i - 2) * 4 + 0] = (__bf16)(v.x * inv); o2[(i - 2) * 4 + 1] = (__bf16)(v.y * inv);
      o2[(i - 2) * 4 + 2] = (__bf16)(v.z * inv); o2[(i - 2) * 4 + 3] = (__bf16)(v.w * inv);
    }
  }
  *(bf16x8*)orow = o1;
  *(bf16x8*)(orow + 8) = o2;
}

// ---------------------------------------------------------------------------
// Logits: out[b, n] = xl[b,:] @ Wout[:, n] + bout[n]; xl staged in LDS.
// ---------------------------------------------------------------------------
__global__ __launch_bounds__(256) void logits_kernel(
    const float* __restrict__ xl, const float* __restrict__ Wout,
    const float* __restrict__ bout, float* __restrict__ out) {
  __shared__ float sx[B][C];
  for (int i = threadIdx.x; i < B * C; i += 256) sx[i / C][i % C] = xl[i];
  __syncthreads();
  int n = blockIdx.x * 256 + threadIdx.x;
  float acc[B] = {};
  for (int k = 0; k < C; ++k) {
    float w = Wout[(size_t)k * V + n];
    #pragma unroll
    for (int b = 0; b < B; ++b) acc[b] += sx[b][k] * w;
  }
  float bb = bout[n];
  #pragma unroll
  for (int b = 0; b < B; ++b) out[(size_t)b * V + n] = acc[b] + bb;
}

// ---------------------------------------------------------------------------
extern "C" void kernel_launch(void* const* d_in, const int* in_sizes, int n_in,
                              void* d_out, int out_size, void* d_ws, size_t ws_size,
                              hipStream_t stream) {
  const int*   idx     = (const int*)  d_in[0];
  const float* tok_emb = (const float*)d_in[1];
  const float* pos_emb = (const float*)d_in[2];
  const float* Wq   = (const float*)d_in[3];
  const float* bq   = (const float*)d_in[4];
  const float* Wk   = (const float*)d_in[5];
  const float* bk   = (const float*)d_in[6];
  const float* Wv   = (const float*)d_in[7];
  const float* bv   = (const float*)d_in[8];
  const float* Wo   = (const float*)d_in[9];
  const float* bo   = (const float*)d_in[10];
  const float* ln1g = (const float*)d_in[11];
  const float* ln1b = (const float*)d_in[12];
  const float* W1   = (const float*)d_in[13];
  const float* b1   = (const float*)d_in[14];
  const float* W2   = (const float*)d_in[15];
  const float* b2   = (const float*)d_in[16];
  const float* ln2g = (const float*)d_in[17];
  const float* ln2b = (const float*)d_in[18];
  const float* lnfg = (const float*)d_in[19];
  const float* lnfb = (const float*)d_in[20];
  const float* Wout = (const float*)d_in[21];
  const float* bout = (const float*)d_in[22];
  float* out = (float*)d_out;

  // workspace layout (≈256 MB)
  char* p = (char*)d_ws;
  float*  x     = (float*)p;   p += (size_t)M * C * 4;        // fp32 residual
  float*  xl    = (float*)p;   p += (size_t)B * C * 4;
  float*  bqkv  = (float*)p;   p += (size_t)L * C3 * 4;
  bf16_t* hb    = (bf16_t*)p;  p += (size_t)M * C * 2;        // LN out / attn out
  bf16_t* qkv   = (bf16_t*)p;  p += (size_t)M * C3 * 2;       // fused QKV
  bf16_t* fb    = (bf16_t*)p;  p += (size_t)M * F * 2;        // FFN hidden
  bf16_t* WqkvT = (bf16_t*)p;  p += (size_t)L * C3 * C * 2;   // [3C][C] per layer
  bf16_t* WoT   = (bf16_t*)p;  p += (size_t)L * C * C * 2;    // [C][C]
  bf16_t* W1T   = (bf16_t*)p;  p += (size_t)L * F * C * 2;    // [F][C]
  bf16_t* W2T   = (bf16_t*)p;  p += (size_t)L * C * F * 2;    // [C][F]

  // weight convert+transpose (once per launch; ~300 MB traffic)
  convw_kernel<<<dim3(C / 32, C / 32, L), 256, 0, stream>>>(Wq, WqkvT,             C, C, (size_t)C3 * C);
  convw_kernel<<<dim3(C / 32, C / 32, L), 256, 0, stream>>>(Wk, WqkvT + (size_t)C * C,     C, C, (size_t)C3 * C);
  convw_kernel<<<dim3(C / 32, C / 32, L), 256, 0, stream>>>(Wv, WqkvT + (size_t)2 * C * C, C, C, (size_t)C3 * C);
  convw_kernel<<<dim3(C / 32, C / 32, L), 256, 0, stream>>>(Wo, WoT, C, C, (size_t)C * C);
  convw_kernel<<<dim3(F / 32, C / 32, L), 256, 0, stream>>>(W1, W1T, C, F, (size_t)F * C);
  convw_kernel<<<dim3(C / 32, F / 32, L), 256, 0, stream>>>(W2, W2T, F, C, (size_t)C * F);
  packb_kernel<<<(L * C3) / 256, 256, 0, stream>>>(bq, bk, bv, bqkv);

  embed_kernel<<<(M * C) / 1024, 256, 0, stream>>>(idx, tok_emb, pos_emb, x);

  for (int l = 0; l < L; ++l) {
    const bf16_t* wqkv = WqkvT + (size_t)l * C3 * C;
    const bf16_t* wo   = WoT   + (size_t)l * C * C;
    const bf16_t* w1   = W1T   + (size_t)l * F * C;
    const bf16_t* w2   = W2T   + (size_t)l * C * F;

    ln_kernel<bf16_t><<<M, 256, 0, stream>>>(x, ln1g + l * C, ln1b + l * C, hb, 1, 0);
    gemm_bf16_kernel<bf16_t><<<dim3(M / 128, C3 / 128), 256, 0, stream>>>(
        hb, wqkv, bqkv + l * C3, nullptr, qkv, C3, C, 0);
    flash_attn_kernel<<<dim3(M / 64, H), 256, 0, stream>>>(qkv, hb);
    gemm_bf16_kernel<float><<<dim3(M / 128, C / 128), 256, 0, stream>>>(
        hb, wo, bo + l * C, x, x, C, C, 0);
    ln_kernel<bf16_t><<<M, 256, 0, stream>>>(x, ln2g + l * C, ln2b + l * C, hb, 1, 0);
    gemm_bf16_kernel<bf16_t><<<dim3(M / 128, F / 128), 256, 0, stream>>>(
        hb, w1, b1 + l * F, nullptr, fb, F, C, 1);
    gemm_bf16_kernel<float><<<dim3(M / 128, C / 128), 256, 0, stream>>>(
        fb, w2, b2 + l * C, x, x, C, F, 0);
  }

  ln_kernel<float><<<B, 256, 0, stream>>>(x, lnfg, lnfb, xl, T, T - 1);
  logits_kernel<<<V / 256, 256, 0, stream>>>(xl, Wout, bout, out);
}

// Round 2
// 2872.585 us; speedup vs baseline: 6.7016x; 2.8734x over previous
//
#include <hip/hip_runtime.h>
#include <math.h>

// Problem constants
constexpr int L = 4, B = 4, T = 2048, C = 1024, H = 16, F = 4096, V = 32000;
constexpr int D = C / H;        // 64
constexpr int M = B * T;        // 8192
constexpr int C3 = 3 * C;       // fused QKV width
constexpr float EPS = 1e-5f;
constexpr float SCLOG2E = 0.125f * 1.44269504088896340736f;  // 1/sqrt(D) * log2(e)

typedef __bf16 bf16_t;
typedef __bf16 bf16x8 __attribute__((ext_vector_type(8)));
typedef __bf16 bf16x4 __attribute__((ext_vector_type(4)));
typedef float  f32x4  __attribute__((ext_vector_type(4)));

#define GLOBAL_AS(p) ((const __attribute__((address_space(1))) void*)(p))
#define LDS_AS(p)    ((__attribute__((address_space(3))) void*)(p))

// ---------------------------------------------------------------------------
// Embedding
// ---------------------------------------------------------------------------
__global__ __launch_bounds__(256) void embed_kernel(
    const int* __restrict__ idx, const float* __restrict__ tok,
    const float* __restrict__ pos, float* __restrict__ x) {
  size_t e4 = ((size_t)blockIdx.x * 256 + threadIdx.x) * 4;
  int row = (int)(e4 / C);
  int c   = (int)(e4 % C);
  int t   = row % T;
  int tokid = idx[row];
  const float4 tv = *(const float4*)(tok + (size_t)tokid * C + c);
  const float4 pv = *(const float4*)(pos + (size_t)t * C + c);
  float4 o;
  o.x = tv.x + pv.x; o.y = tv.y + pv.y; o.z = tv.z + pv.z; o.w = tv.w + pv.w;
  *(float4*)(x + e4) = o;
}

// ---------------------------------------------------------------------------
// LayerNorm (fp32 in, bf16 or fp32 out)
// ---------------------------------------------------------------------------
template <typename OutT>
__global__ __launch_bounds__(256) void ln_kernel(
    const float* __restrict__ xin, const float* __restrict__ g,
    const float* __restrict__ bta, OutT* __restrict__ out,
    int rowMul, int rowAdd) {
  int row_in = blockIdx.x * rowMul + rowAdd;
  const float* xr = xin + (size_t)row_in * C;
  int c = threadIdx.x * 4;
  float4 xv = *(const float4*)(xr + c);
  float s  = xv.x + xv.y + xv.z + xv.w;
  float ss = xv.x * xv.x + xv.y * xv.y + xv.z * xv.z + xv.w * xv.w;
  #pragma unroll
  for (int off = 32; off > 0; off >>= 1) {
    s  += __shfl_xor(s, off);
    ss += __shfl_xor(ss, off);
  }
  __shared__ float sh[8];
  int wid = threadIdx.x >> 6, lane = threadIdx.x & 63;
  if (lane == 0) { sh[wid * 2] = s; sh[wid * 2 + 1] = ss; }
  __syncthreads();
  s  = sh[0] + sh[2] + sh[4] + sh[6];
  ss = sh[1] + sh[3] + sh[5] + sh[7];
  float mean = s / C;
  float var  = ss / C - mean * mean;
  float inv  = rsqrtf(var + EPS);
  float4 gv = *(const float4*)(g + c);
  float4 bv = *(const float4*)(bta + c);
  float o0 = (xv.x - mean) * inv * gv.x + bv.x;
  float o1 = (xv.y - mean) * inv * gv.y + bv.y;
  float o2 = (xv.z - mean) * inv * gv.z + bv.z;
  float o3 = (xv.w - mean) * inv * gv.w + bv.w;
  if constexpr (sizeof(OutT) == 2) {
    bf16x4 ov;
    ov[0] = (__bf16)o0; ov[1] = (__bf16)o1; ov[2] = (__bf16)o2; ov[3] = (__bf16)o3;
    *(bf16x4*)(out + (size_t)blockIdx.x * C + c) = ov;
  } else {
    float4 o; o.x = o0; o.y = o1; o.z = o2; o.w = o3;
    *(float4*)(out + (size_t)blockIdx.x * C + c) = o;
  }
}

// ---------------------------------------------------------------------------
// Weight convert+transpose: W[K][N] fp32 -> Wt[N][K] bf16 (per-layer via z).
// ---------------------------------------------------------------------------
__global__ __launch_bounds__(256) void convw_kernel(
    const float* __restrict__ W, bf16_t* __restrict__ Wt,
    int K, int N, size_t dstL) {
  const size_t soff = (size_t)blockIdx.z * K * N;
  const size_t doff = (size_t)blockIdx.z * dstL;
  __shared__ float s[32][33];
  int n0 = blockIdx.x * 32, k0 = blockIdx.y * 32;
  int tx = threadIdx.x & 31, ty = threadIdx.x >> 5;  // 32 x 8
  #pragma unroll
  for (int i = 0; i < 4; ++i)
    s[ty + i * 8][tx] = W[soff + (size_t)(k0 + ty + i * 8) * N + n0 + tx];
  __syncthreads();
  #pragma unroll
  for (int i = 0; i < 4; ++i)
    Wt[doff + (size_t)(n0 + ty + i * 8) * K + k0 + tx] = (__bf16)s[tx][ty + i * 8];
}

// Pack bq|bk|bv -> bqkv[L][3C]
__global__ __launch_bounds__(256) void packb_kernel(
    const float* __restrict__ bq, const float* __restrict__ bk,
    const float* __restrict__ bv, float* __restrict__ bqkv) {
  int i = blockIdx.x * 256 + threadIdx.x;       // < L*3C
  int l = i / C3, r = i % C3, sec = r / C, c = r % C;
  const float* src = (sec == 0) ? bq : (sec == 1) ? bk : bv;
  bqkv[i] = src[l * C + c];
}

// ---------------------------------------------------------------------------
// V transpose: qkv[:, 2C:3C] per batch [T][C] -> vt[b][C][T] (bf16)
// ---------------------------------------------------------------------------
__global__ __launch_bounds__(256) void transpose_v_kernel(
    const bf16_t* __restrict__ qkv, bf16_t* __restrict__ vt) {
  const int bb = blockIdx.z;
  __shared__ bf16_t s[32][33];
  int t0 = blockIdx.x * 32, c0 = blockIdx.y * 32;
  int tx = threadIdx.x & 31, ty = threadIdx.x >> 5;  // 32 x 8
  #pragma unroll
  for (int i = 0; i < 4; ++i)
    s[ty + i * 8][tx] = qkv[(size_t)(bb * T + t0 + ty + i * 8) * C3 + 2 * C + c0 + tx];
  __syncthreads();
  #pragma unroll
  for (int i = 0; i < 4; ++i)
    vt[(size_t)(bb * C + c0 + ty + i * 8) * T + t0 + tx] = s[tx][ty + i * 8];
}

// ---------------------------------------------------------------------------
// bf16 MFMA GEMM (unchanged from round 1; verified fragment mappings)
// ---------------------------------------------------------------------------
template <typename OutT>
__global__ __launch_bounds__(256) void gemm_bf16_kernel(
    const bf16_t* __restrict__ A, const bf16_t* __restrict__ Bt,
    const float* __restrict__ bias, const float* resid,
    OutT* Cout, int N, int K, int relu) {
  constexpr int BK = 64;
  __shared__ bf16_t sA[128 * BK];
  __shared__ bf16_t sB[128 * BK];
  const int tid = threadIdx.x;
  const int row0 = blockIdx.x * 128;
  const int col0 = blockIdx.y * 128;
  const int wv = tid >> 6, l = tid & 63;
  const int wm = wv >> 1, wn = wv & 1;

  const int sr  = tid >> 3;
  const int seg = tid & 7;
  const int ssw = (seg ^ (sr & 7)) * 8;

  const int lc = l & 15, lg = l >> 4;
  const int sw = (l & 7) << 4;

  f32x4 acc[4][4] = {};

  for (int k0 = 0; k0 < K; k0 += BK) {
    __syncthreads();
    #pragma unroll
    for (int i = 0; i < 4; ++i) {
      const bf16_t* ga = A  + (size_t)(row0 + i * 32 + sr) * K + k0 + ssw;
      const bf16_t* gb = Bt + (size_t)(col0 + i * 32 + sr) * K + k0 + ssw;
      __builtin_amdgcn_global_load_lds(GLOBAL_AS(ga),
          LDS_AS((char*)sA + i * 4096 + wv * 1024), 16, 0, 0);
      __builtin_amdgcn_global_load_lds(GLOBAL_AS(gb),
          LDS_AS((char*)sB + i * 4096 + wv * 1024), 16, 0, 0);
    }
    __syncthreads();
    #pragma unroll
    for (int ks = 0; ks < 2; ++ks) {
      const int bco = ks * 64 + lg * 16;
      const int bph = bco ^ sw;
      bf16x8 af[4], bfr[4];
      #pragma unroll
      for (int i = 0; i < 4; ++i) {
        af[i]  = *(const bf16x8*)((const char*)sA +
                   (size_t)((wm * 64 + i * 16 + lc) * 128 + bph));
        bfr[i] = *(const bf16x8*)((const char*)sB +
                   (size_t)((wn * 64 + i * 16 + lc) * 128 + bph));
      }
      #pragma unroll
      for (int i = 0; i < 4; ++i)
        #pragma unroll
        for (int j = 0; j < 4; ++j)
          acc[i][j] = __builtin_amdgcn_mfma_f32_16x16x32_bf16(
              af[i], bfr[j], acc[i][j], 0, 0, 0);
    }
  }

  float bsv[4];
  #pragma unroll
  for (int j = 0; j < 4; ++j) bsv[j] = bias[col0 + wn * 64 + j * 16 + lc];
  #pragma unroll
  for (int i = 0; i < 4; ++i) {
    #pragma unroll
    for (int r = 0; r < 4; ++r) {
      int rr = row0 + wm * 64 + i * 16 + lg * 4 + r;
      const float* resrow = resid ? resid + (size_t)rr * N : nullptr;
      #pragma unroll
      for (int j = 0; j < 4; ++j) {
        int cc = col0 + wn * 64 + j * 16 + lc;
        float v = acc[i][j][r] + bsv[j];
        if (relu) v = fmaxf(v, 0.f);
        if (resrow) v += resrow[cc];
        Cout[(size_t)rr * N + cc] = (OutT)v;
      }
    }
  }
}

// ---------------------------------------------------------------------------
// MFMA flash attention. Block = (b,h) x 128 q-rows; 4 waves x 32 q-rows.
// K tile [64 kt][64 d], Vt tile [64 d][64 kt] in LDS (bf16, XOR-swizzled,
// staged via global_load_lds w/ inverse-swizzled source). QK^T and P@V via
// mfma_f32_16x16x32_bf16. P round-trips through per-wave swizzled LDS.
// Online softmax fp32, base-2 (scale*log2e folded into scores).
// ---------------------------------------------------------------------------
__global__ __launch_bounds__(256) void attn_mfma_kernel(
    const bf16_t* __restrict__ qkv, const bf16_t* __restrict__ vt,
    bf16_t* __restrict__ out) {
  const int h  = blockIdx.y;
  const int qtile = (int)gridDim.x - 1 - (int)blockIdx.x;  // long blocks first
  const int qb = qtile * 128;
  const int b  = qb / T;
  const int t0 = qb % T;
  const int tid = threadIdx.x;
  const int wv = tid >> 6, l = tid & 63;
  const int lc = l & 15, lg = l >> 4;
  const int ksw = (lc & 7) << 4;   // read-side swizzle key (row&7)<<4, row≡lc mod 8

  __shared__ bf16_t sK[64 * 64];       // [kt][d]
  __shared__ bf16_t sVt[64 * 64];      // [d][kt]
  __shared__ bf16_t sP[4][32 * 64];    // per-wave [q][kt]

  // Q fragments: q = qb + wv*32 + mi*16 + lc ; d = ki*32 + lg*8 + e
  bf16x8 qf[2][2];
  {
    const bf16_t* qp = qkv + (size_t)(qb + wv * 32 + lc) * C3 + h * D + lg * 8;
    #pragma unroll
    for (int mi = 0; mi < 2; ++mi)
      #pragma unroll
      for (int ki = 0; ki < 2; ++ki)
        qf[mi][ki] = *(const bf16x8*)(qp + (size_t)mi * 16 * C3 + ki * 32);
  }

  // staging source pointers (per lane): instr j=wv*2+ii covers rows j*8+srow
  const int srow = (l >> 3) & 7;
  const int schk = l & 7;
  const bf16_t* kgp[2];
  const bf16_t* vgp[2];
  #pragma unroll
  for (int ii = 0; ii < 2; ++ii) {
    int r = (wv * 2 + ii) * 8 + srow;
    kgp[ii] = qkv + (size_t)(b * T + r) * C3 + C + h * D + (schk ^ srow) * 8;
    vgp[ii] = vt + (size_t)(b * C + h * D + r) * T + (schk ^ srow) * 8;
  }

  f32x4 of[2][4] = {};          // O accumulator [mi][dj]
  float mrow[2][4], lrow[2][4];
  #pragma unroll
  for (int mi = 0; mi < 2; ++mi)
    #pragma unroll
    for (int r = 0; r < 4; ++r) { mrow[mi][r] = -1e30f; lrow[mi][r] = 0.f; }

  const int ntiles = (t0 + 127) / 64 + 1;
  const int twave_max = t0 + wv * 32 + 31;
  char* const pb = (char*)sP[wv];

  for (int it = 0; it < ntiles; ++it) {
    const int kt0 = it * 64;
    __syncthreads();
    #pragma unroll
    for (int ii = 0; ii < 2; ++ii) {
      __builtin_amdgcn_global_load_lds(GLOBAL_AS(kgp[ii]),
          LDS_AS((char*)sK + (wv * 2 + ii) * 1024), 16, 0, 0);
      __builtin_amdgcn_global_load_lds(GLOBAL_AS(vgp[ii]),
          LDS_AS((char*)sVt + (wv * 2 + ii) * 1024), 16, 0, 0);
      kgp[ii] += (size_t)64 * C3;
      vgp[ii] += 64;
    }
    __syncthreads();

    if (kt0 <= twave_max) {
      // ---- S = Q @ K^T (fp32 accum) ----
      f32x4 s[2][4] = {};
      #pragma unroll
      for (int ni = 0; ni < 4; ++ni) {
        #pragma unroll
        for (int ki = 0; ki < 2; ++ki) {
          int off = (ni * 16 + lc) * 128 + ((ki * 64 + lg * 16) ^ ksw);
          bf16x8 kf = *(const bf16x8*)((const char*)sK + off);
          s[0][ni] = __builtin_amdgcn_mfma_f32_16x16x32_bf16(qf[0][ki], kf, s[0][ni], 0, 0, 0);
          s[1][ni] = __builtin_amdgcn_mfma_f32_16x16x32_bf16(qf[1][ki], kf, s[1][ni], 0, 0, 0);
        }
      }
      // ---- scale (+causal mask on diagonal tiles) ----
      const bool diag = (kt0 + 63 > t0 + wv * 32);
      #pragma unroll
      for (int mi = 0; mi < 2; ++mi)
        #pragma unroll
        for (int ni = 0; ni < 4; ++ni)
          #pragma unroll
          for (int r = 0; r < 4; ++r) {
            float v = s[mi][ni][r] * SCLOG2E;
            if (diag) {
              int ktg = kt0 + ni * 16 + lc;
              int tq  = t0 + wv * 32 + mi * 16 + lg * 4 + r;
              if (ktg > tq) v = -1e30f;
            }
            s[mi][ni][r] = v;
          }
      // ---- online softmax (base 2) ----
      #pragma unroll
      for (int mi = 0; mi < 2; ++mi) {
        #pragma unroll
        for (int r = 0; r < 4; ++r) {
          float rm = fmaxf(fmaxf(s[mi][0][r], s[mi][1][r]),
                           fmaxf(s[mi][2][r], s[mi][3][r]));
          rm = fmaxf(rm, __shfl_xor(rm, 1));
          rm = fmaxf(rm, __shfl_xor(rm, 2));
          rm = fmaxf(rm, __shfl_xor(rm, 4));
          rm = fmaxf(rm, __shfl_xor(rm, 8));
          float mnew = fmaxf(mrow[mi][r], rm);
          float corr = exp2f(mrow[mi][r] - mnew);
          mrow[mi][r] = mnew;
          float psum = 0.f;
          #pragma unroll
          for (int ni = 0; ni < 4; ++ni) {
            float p = exp2f(s[mi][ni][r] - mnew);
            s[mi][ni][r] = p;
            psum += p;
          }
          psum += __shfl_xor(psum, 1);
          psum += __shfl_xor(psum, 2);
          psum += __shfl_xor(psum, 4);
          psum += __shfl_xor(psum, 8);
          lrow[mi][r] = lrow[mi][r] * corr + psum;
          #pragma unroll
          for (int dj = 0; dj < 4; ++dj) of[mi][dj][r] *= corr;
        }
      }
      // ---- P -> bf16 -> per-wave LDS (swizzled [q][kt]) ----
      #pragma unroll
      for (int mi = 0; mi < 2; ++mi)
        #pragma unroll
        for (int ni = 0; ni < 4; ++ni)
          #pragma unroll
          for (int r = 0; r < 4; ++r) {
            int q = mi * 16 + lg * 4 + r;
            int off = q * 128 + ((ni * 32 + lc * 2) ^ ((q & 7) << 4));
            *(bf16_t*)(pb + off) = (bf16_t)s[mi][ni][r];
          }
      asm volatile("s_waitcnt lgkmcnt(0)" ::: "memory");
      __builtin_amdgcn_sched_barrier(0);
      // ---- O += P @ V  (A=P from LDS, B=Vt rows) ----
      #pragma unroll
      for (int ktc = 0; ktc < 2; ++ktc) {
        bf16x8 pf[2];
        #pragma unroll
        for (int mi = 0; mi < 2; ++mi) {
          int off = (mi * 16 + lc) * 128 + ((ktc * 64 + lg * 16) ^ ksw);
          pf[mi] = *(const bf16x8*)(pb + off);
        }
        #pragma unroll
        for (int dj = 0; dj < 4; ++dj) {
          int off = (dj * 16 + lc) * 128 + ((ktc * 64 + lg * 16) ^ ksw);
          bf16x8 vf = *(const bf16x8*)((const char*)sVt + off);
          #pragma unroll
          for (int mi = 0; mi < 2; ++mi)
            of[mi][dj] = __builtin_amdgcn_mfma_f32_16x16x32_bf16(pf[mi], vf, of[mi][dj], 0, 0, 0);
        }
      }
    }
  }

  // ---- normalize + write out (bf16) ----
  #pragma unroll
  for (int mi = 0; mi < 2; ++mi) {
    #pragma unroll
    for (int r = 0; r < 4; ++r) {
      float inv = 1.f / lrow[mi][r];
      int row = qb + wv * 32 + mi * 16 + lg * 4 + r;
      bf16_t* orow = out + (size_t)row * C + h * D;
      #pragma unroll
      for (int dj = 0; dj < 4; ++dj)
        orow[dj * 16 + lc] = (bf16_t)(of[mi][dj][r] * inv);
    }
  }
}

// ---------------------------------------------------------------------------
// Logits
// ---------------------------------------------------------------------------
__global__ __launch_bounds__(256) void logits_kernel(
    const float* __restrict__ xl, const float* __restrict__ Wout,
    const float* __restrict__ bout, float* __restrict__ out) {
  __shared__ float sx[B][C];
  for (int i = threadIdx.x; i < B * C; i += 256) sx[i / C][i % C] = xl[i];
  __syncthreads();
  int n = blockIdx.x * 256 + threadIdx.x;
  float acc[B] = {};
  for (int k = 0; k < C; ++k) {
    float w = Wout[(size_t)k * V + n];
    #pragma unroll
    for (int b = 0; b < B; ++b) acc[b] += sx[b][k] * w;
  }
  float bb = bout[n];
  #pragma unroll
  for (int b = 0; b < B; ++b) out[(size_t)b * V + n] = acc[b] + bb;
}

// ---------------------------------------------------------------------------
extern "C" void kernel_launch(void* const* d_in, const int* in_sizes, int n_in,
                              void* d_out, int out_size, void* d_ws, size_t ws_size,
                              hipStream_t stream) {
  const int*   idx     = (const int*)  d_in[0];
  const float* tok_emb = (const float*)d_in[1];
  const float* pos_emb = (const float*)d_in[2];
  const float* Wq   = (const float*)d_in[3];
  const float* bq   = (const float*)d_in[4];
  const float* Wk   = (const float*)d_in[5];
  const float* bk   = (const float*)d_in[6];
  const float* Wv   = (const float*)d_in[7];
  const float* bv   = (const float*)d_in[8];
  const float* Wo   = (const float*)d_in[9];
  const float* bo   = (const float*)d_in[10];
  const float* ln1g = (const float*)d_in[11];
  const float* ln1b = (const float*)d_in[12];
  const float* W1   = (const float*)d_in[13];
  const float* b1   = (const float*)d_in[14];
  const float* W2   = (const float*)d_in[15];
  const float* b2   = (const float*)d_in[16];
  const float* ln2g = (const float*)d_in[17];
  const float* ln2b = (const float*)d_in[18];
  const float* lnfg = (const float*)d_in[19];
  const float* lnfb = (const float*)d_in[20];
  const float* Wout = (const float*)d_in[21];
  const float* bout = (const float*)d_in[22];
  float* out = (float*)d_out;

  // workspace layout
  char* p = (char*)d_ws;
  float*  x     = (float*)p;   p += (size_t)M * C * 4;        // fp32 residual
  float*  xl    = (float*)p;   p += (size_t)B * C * 4;
  float*  bqkv  = (float*)p;   p += (size_t)L * C3 * 4;
  bf16_t* hb    = (bf16_t*)p;  p += (size_t)M * C * 2;        // LN out / attn out
  bf16_t* qkv   = (bf16_t*)p;  p += (size_t)M * C3 * 2;       // fused QKV
  bf16_t* fb    = (bf16_t*)p;  p += (size_t)M * F * 2;        // FFN hidden
  bf16_t* WqkvT = (bf16_t*)p;  p += (size_t)L * C3 * C * 2;
  bf16_t* WoT   = (bf16_t*)p;  p += (size_t)L * C * C * 2;
  bf16_t* W1T   = (bf16_t*)p;  p += (size_t)L * F * C * 2;
  bf16_t* W2T   = (bf16_t*)p;  p += (size_t)L * C * F * 2;
  bf16_t* vt    = fb;   // aliased: vt (B*C*T bf16 = 16MB) used only during attn

  convw_kernel<<<dim3(C / 32, C / 32, L), 256, 0, stream>>>(Wq, WqkvT,             C, C, (size_t)C3 * C);
  convw_kernel<<<dim3(C / 32, C / 32, L), 256, 0, stream>>>(Wk, WqkvT + (size_t)C * C,     C, C, (size_t)C3 * C);
  convw_kernel<<<dim3(C / 32, C / 32, L), 256, 0, stream>>>(Wv, WqkvT + (size_t)2 * C * C, C, C, (size_t)C3 * C);
  convw_kernel<<<dim3(C / 32, C / 32, L), 256, 0, stream>>>(Wo, WoT, C, C, (size_t)C * C);
  convw_kernel<<<dim3(F / 32, C / 32, L), 256, 0, stream>>>(W1, W1T, C, F, (size_t)F * C);
  convw_kernel<<<dim3(C / 32, F / 32, L), 256, 0, stream>>>(W2, W2T, F, C, (size_t)C * F);
  packb_kernel<<<(L * C3) / 256, 256, 0, stream>>>(bq, bk, bv, bqkv);

  embed_kernel<<<(M * C) / 1024, 256, 0, stream>>>(idx, tok_emb, pos_emb, x);

  for (int l = 0; l < L; ++l) {
    const bf16_t* wqkv = WqkvT + (size_t)l * C3 * C;
    const bf16_t* wo   = WoT   + (size_t)l * C * C;
    const bf16_t* w1   = W1T   + (size_t)l * F * C;
    const bf16_t* w2   = W2T   + (size_t)l * C * F;

    ln_kernel<bf16_t><<<M, 256, 0, stream>>>(x, ln1g + l * C, ln1b + l * C, hb, 1, 0);
    gemm_bf16_kernel<bf16_t><<<dim3(M / 128, C3 / 128), 256, 0, stream>>>(
        hb, wqkv, bqkv + l * C3, nullptr, qkv, C3, C, 0);
    transpose_v_kernel<<<dim3(T / 32, C / 32, B), 256, 0, stream>>>(qkv, vt);
    attn_mfma_kernel<<<dim3(M / 128, H), 256, 0, stream>>>(qkv, vt, hb);
    gemm_bf16_kernel<float><<<dim3(M / 128, C / 128), 256, 0, stream>>>(
        hb, wo, bo + l * C, x, x, C, C, 0);
    ln_kernel<bf16_t><<<M, 256, 0, stream>>>(x, ln2g + l * C, ln2b + l * C, hb, 1, 0);
    gemm_bf16_kernel<bf16_t><<<dim3(M / 128, F / 128), 256, 0, stream>>>(
        hb, w1, b1 + l * F, nullptr, fb, F, C, 1);
    gemm_bf16_kernel<float><<<dim3(M / 128, C / 128), 256, 0, stream>>>(
        fb, w2, b2 + l * C, x, x, C, F, 0);
  }

  ln_kernel<float><<<B, 256, 0, stream>>>(x, lnfg, lnfb, xl, T, T - 1);
  logits_kernel<<<V / 256, 256, 0, stream>>>(xl, Wout, bout, out);
}

// Round 3
// 2398.064 us; speedup vs baseline: 8.0277x; 1.1979x over previous
//
#include <hip/hip_runtime.h>
#include <math.h>

// Problem constants
constexpr int L = 4, B = 4, T = 2048, C = 1024, H = 16, F = 4096, V = 32000;
constexpr int D = C / H;        // 64
constexpr int M = B * T;        // 8192
constexpr int C3 = 3 * C;       // fused QKV width
constexpr float EPS = 1e-5f;
constexpr float SCLOG2E = 0.125f * 1.44269504088896340736f;  // 1/sqrt(D) * log2(e)
constexpr int KSPL = 8;         // logits k-split

typedef __bf16 bf16_t;
typedef __bf16 bf16x8 __attribute__((ext_vector_type(8)));
typedef __bf16 bf16x4 __attribute__((ext_vector_type(4)));
typedef __bf16 bf16x2 __attribute__((ext_vector_type(2)));
typedef float  f32x4  __attribute__((ext_vector_type(4)));
typedef float  f32x16 __attribute__((ext_vector_type(16)));

#define GLOBAL_AS(p) ((const __attribute__((address_space(1))) void*)(p))
#define LDS_AS(p)    ((__attribute__((address_space(3))) void*)(p))

// ---------------------------------------------------------------------------
// Embedding
// ---------------------------------------------------------------------------
__global__ __launch_bounds__(256) void embed_kernel(
    const int* __restrict__ idx, const float* __restrict__ tok,
    const float* __restrict__ pos, float* __restrict__ x) {
  size_t e4 = ((size_t)blockIdx.x * 256 + threadIdx.x) * 4;
  int row = (int)(e4 / C);
  int c   = (int)(e4 % C);
  int t   = row % T;
  int tokid = idx[row];
  const float4 tv = *(const float4*)(tok + (size_t)tokid * C + c);
  const float4 pv = *(const float4*)(pos + (size_t)t * C + c);
  float4 o;
  o.x = tv.x + pv.x; o.y = tv.y + pv.y; o.z = tv.z + pv.z; o.w = tv.w + pv.w;
  *(float4*)(x + e4) = o;
}

// ---------------------------------------------------------------------------
// LayerNorm (fp32 in, bf16 or fp32 out)
// ---------------------------------------------------------------------------
template <typename OutT>
__global__ __launch_bounds__(256) void ln_kernel(
    const float* __restrict__ xin, const float* __restrict__ g,
    const float* __restrict__ bta, OutT* __restrict__ out,
    int rowMul, int rowAdd) {
  int row_in = blockIdx.x * rowMul + rowAdd;
  const float* xr = xin + (size_t)row_in * C;
  int c = threadIdx.x * 4;
  float4 xv = *(const float4*)(xr + c);
  float s  = xv.x + xv.y + xv.z + xv.w;
  float ss = xv.x * xv.x + xv.y * xv.y + xv.z * xv.z + xv.w * xv.w;
  #pragma unroll
  for (int off = 32; off > 0; off >>= 1) {
    s  += __shfl_xor(s, off);
    ss += __shfl_xor(ss, off);
  }
  __shared__ float sh[8];
  int wid = threadIdx.x >> 6, lane = threadIdx.x & 63;
  if (lane == 0) { sh[wid * 2] = s; sh[wid * 2 + 1] = ss; }
  __syncthreads();
  s  = sh[0] + sh[2] + sh[4] + sh[6];
  ss = sh[1] + sh[3] + sh[5] + sh[7];
  float mean = s / C;
  float var  = ss / C - mean * mean;
  float inv  = rsqrtf(var + EPS);
  float4 gv = *(const float4*)(g + c);
  float4 bv = *(const float4*)(bta + c);
  float o0 = (xv.x - mean) * inv * gv.x + bv.x;
  float o1 = (xv.y - mean) * inv * gv.y + bv.y;
  float o2 = (xv.z - mean) * inv * gv.z + bv.z;
  float o3 = (xv.w - mean) * inv * gv.w + bv.w;
  if constexpr (sizeof(OutT) == 2) {
    bf16x4 ov;
    ov[0] = (__bf16)o0; ov[1] = (__bf16)o1; ov[2] = (__bf16)o2; ov[3] = (__bf16)o3;
    *(bf16x4*)(out + (size_t)blockIdx.x * C + c) = ov;
  } else {
    float4 o; o.x = o0; o.y = o1; o.z = o2; o.w = o3;
    *(float4*)(out + (size_t)blockIdx.x * C + c) = o;
  }
}

// ---------------------------------------------------------------------------
// Weight convert+transpose: W[K][N] fp32 -> Wt[N][K] bf16 (per-layer via z).
// ---------------------------------------------------------------------------
__global__ __launch_bounds__(256) void convw_kernel(
    const float* __restrict__ W, bf16_t* __restrict__ Wt,
    int K, int N, size_t dstL) {
  const size_t soff = (size_t)blockIdx.z * K * N;
  const size_t doff = (size_t)blockIdx.z * dstL;
  __shared__ float s[32][33];
  int n0 = blockIdx.x * 32, k0 = blockIdx.y * 32;
  int tx = threadIdx.x & 31, ty = threadIdx.x >> 5;  // 32 x 8
  #pragma unroll
  for (int i = 0; i < 4; ++i)
    s[ty + i * 8][tx] = W[soff + (size_t)(k0 + ty + i * 8) * N + n0 + tx];
  __syncthreads();
  #pragma unroll
  for (int i = 0; i < 4; ++i)
    Wt[doff + (size_t)(n0 + ty + i * 8) * K + k0 + tx] = (__bf16)s[tx][ty + i * 8];
}

// Pack bq|bk|bv -> bqkv[L][3C]
__global__ __launch_bounds__(256) void packb_kernel(
    const float* __restrict__ bq, const float* __restrict__ bk,
    const float* __restrict__ bv, float* __restrict__ bqkv) {
  int i = blockIdx.x * 256 + threadIdx.x;       // < L*3C
  int l = i / C3, r = i % C3, sec = r / C, c = r % C;
  const float* src = (sec == 0) ? bq : (sec == 1) ? bk : bv;
  bqkv[i] = src[l * C + c];
}

// ---------------------------------------------------------------------------
// V transpose: qkv[:, 2C:3C] per batch [T][C] -> vt[b][C][T] (bf16)
// ---------------------------------------------------------------------------
__global__ __launch_bounds__(256) void transpose_v_kernel(
    const bf16_t* __restrict__ qkv, bf16_t* __restrict__ vt) {
  const int bb = blockIdx.z;
  __shared__ bf16_t s[32][33];
  int t0 = blockIdx.x * 32, c0 = blockIdx.y * 32;
  int tx = threadIdx.x & 31, ty = threadIdx.x >> 5;  // 32 x 8
  #pragma unroll
  for (int i = 0; i < 4; ++i)
    s[ty + i * 8][tx] = qkv[(size_t)(bb * T + t0 + ty + i * 8) * C3 + 2 * C + c0 + tx];
  __syncthreads();
  #pragma unroll
  for (int i = 0; i < 4; ++i)
    vt[(size_t)(bb * C + c0 + ty + i * 8) * T + t0 + tx] = s[tx][ty + i * 8];
}

// ---------------------------------------------------------------------------
// bf16 MFMA GEMM (m97 structure) + bijective XCD swizzle on M-tiles (T1)
// ---------------------------------------------------------------------------
template <typename OutT>
__global__ __launch_bounds__(256) void gemm_bf16_kernel(
    const bf16_t* __restrict__ A, const bf16_t* __restrict__ Bt,
    const float* __restrict__ bias, const float* resid,
    OutT* Cout, int N, int K, int relu) {
  constexpr int BK = 64;
  __shared__ bf16_t sA[128 * BK];
  __shared__ bf16_t sB[128 * BK];
  const int tid = threadIdx.x;
  int bx = (int)blockIdx.x;
  if (((int)gridDim.x & 7) == 0)                 // XCD-contiguous M-bands
    bx = (bx & 7) * ((int)gridDim.x >> 3) + (bx >> 3);
  const int row0 = bx * 128;
  const int col0 = blockIdx.y * 128;
  const int wv = tid >> 6, l = tid & 63;
  const int wm = wv >> 1, wn = wv & 1;

  const int sr  = tid >> 3;
  const int seg = tid & 7;
  const int ssw = (seg ^ (sr & 7)) * 8;

  const int lc = l & 15, lg = l >> 4;
  const int sw = (l & 7) << 4;

  f32x4 acc[4][4] = {};

  for (int k0 = 0; k0 < K; k0 += BK) {
    __syncthreads();
    #pragma unroll
    for (int i = 0; i < 4; ++i) {
      const bf16_t* ga = A  + (size_t)(row0 + i * 32 + sr) * K + k0 + ssw;
      const bf16_t* gb = Bt + (size_t)(col0 + i * 32 + sr) * K + k0 + ssw;
      __builtin_amdgcn_global_load_lds(GLOBAL_AS(ga),
          LDS_AS((char*)sA + i * 4096 + wv * 1024), 16, 0, 0);
      __builtin_amdgcn_global_load_lds(GLOBAL_AS(gb),
          LDS_AS((char*)sB + i * 4096 + wv * 1024), 16, 0, 0);
    }
    __syncthreads();
    #pragma unroll
    for (int ks = 0; ks < 2; ++ks) {
      const int bco = ks * 64 + lg * 16;
      const int bph = bco ^ sw;
      bf16x8 af[4], bfr[4];
      #pragma unroll
      for (int i = 0; i < 4; ++i) {
        af[i]  = *(const bf16x8*)((const char*)sA +
                   (size_t)((wm * 64 + i * 16 + lc) * 128 + bph));
        bfr[i] = *(const bf16x8*)((const char*)sB +
                   (size_t)((wn * 64 + i * 16 + lc) * 128 + bph));
      }
      #pragma unroll
      for (int i = 0; i < 4; ++i)
        #pragma unroll
        for (int j = 0; j < 4; ++j)
          acc[i][j] = __builtin_amdgcn_mfma_f32_16x16x32_bf16(
              af[i], bfr[j], acc[i][j], 0, 0, 0);
    }
  }

  float bsv[4];
  #pragma unroll
  for (int j = 0; j < 4; ++j) bsv[j] = bias[col0 + wn * 64 + j * 16 + lc];
  #pragma unroll
  for (int i = 0; i < 4; ++i) {
    #pragma unroll
    for (int r = 0; r < 4; ++r) {
      int rr = row0 + wm * 64 + i * 16 + lg * 4 + r;
      const float* resrow = resid ? resid + (size_t)rr * N : nullptr;
      #pragma unroll
      for (int j = 0; j < 4; ++j) {
        int cc = col0 + wn * 64 + j * 16 + lc;
        float v = acc[i][j][r] + bsv[j];
        if (relu) v = fmaxf(v, 0.f);
        if (resrow) v += resrow[cc];
        Cout[(size_t)rr * N + cc] = (OutT)v;
      }
    }
  }
}

// ---------------------------------------------------------------------------
// MFMA flash attention, swapped-QK^T 32x32 form, double-buffered K/V.
// Block = (b,h) x 128 q-rows; 4 waves x 32 q-rows. KVBLK=64.
// S^T = mfma(K, Q): lane owns one q-row (32 kt split 16/16 with lane^32).
// Softmax fully in-register (1 shfl_xor(32) per reduction). P -> A-frag via
// packed-word shfl_xor(32). O accumulated transposed: O^T = V^T @ P^T.
// Epilogue transposes O through per-wave LDS for coalesced bf16 output.
// ---------------------------------------------------------------------------
__global__ __launch_bounds__(256) void attn_mfma_kernel(
    const bf16_t* __restrict__ qkv, const bf16_t* __restrict__ vt,
    bf16_t* __restrict__ out) {
  const int h  = blockIdx.y;
  const int qtile = (int)gridDim.x - 1 - (int)blockIdx.x;  // long blocks first
  const int qb = qtile * 128;
  const int b  = qb / T;
  const int t0 = qb % T;
  const int tid = threadIdx.x;
  const int wv = tid >> 6, l = tid & 63;
  const int lq = l & 31;           // q col / kt row / d row within 32-tile
  const int hi = l >> 5;

  __shared__ bf16_t sK[2][64 * 64];    // [buf][kt][d]
  __shared__ bf16_t sVt[2][64 * 64];   // [buf][d][kt]

  // Q B-fragments (pre-scaled): q = qb+wv*32+lq ; k = ks*16 + hi*8 + e
  bf16x8 qf[4];
  {
    const bf16_t* qp = qkv + (size_t)(qb + wv * 32 + lq) * C3 + h * D + hi * 8;
    #pragma unroll
    for (int ks = 0; ks < 4; ++ks) {
      bf16x8 raw = *(const bf16x8*)(qp + ks * 16);
      #pragma unroll
      for (int e = 0; e < 8; ++e) qf[ks][e] = (__bf16)((float)raw[e] * SCLOG2E);
    }
  }

  // staging source pointers: K instr j=wv*2+ii covers rows 8j..8j+7
  const int srow = (l >> 3) & 7;
  const int schk = l & 7;
  const bf16_t* kgp[2];
  const bf16_t* vgp[2];
  #pragma unroll
  for (int ii = 0; ii < 2; ++ii) {
    int r = (wv * 2 + ii) * 8 + srow;
    kgp[ii] = qkv + (size_t)(b * T + r) * C3 + C + h * D + (schk ^ srow) * 8;
    vgp[ii] = vt + (size_t)(b * C + h * D + r) * T + (schk ^ srow) * 8;
  }

  f32x16 of[2] = {};              // O^T accumulator: d-tiles, col q=lq
  float m = -1e30f, lsum = 0.f;

  const int ntiles = (t0 + 127) / 64 + 1;
  const int tq = t0 + wv * 32 + lq;
  const int twave_lo = t0 + wv * 32;
  const int twave_hi = twave_lo + 31;

  auto STAGE = [&](int buf) {
    #pragma unroll
    for (int ii = 0; ii < 2; ++ii) {
      __builtin_amdgcn_global_load_lds(GLOBAL_AS(kgp[ii]),
          LDS_AS((char*)sK[buf] + (wv * 2 + ii) * 1024), 16, 0, 0);
      __builtin_amdgcn_global_load_lds(GLOBAL_AS(vgp[ii]),
          LDS_AS((char*)sVt[buf] + (wv * 2 + ii) * 1024), 16, 0, 0);
      kgp[ii] += (size_t)64 * C3;
      vgp[ii] += 64;
    }
  };

  STAGE(0);
  __syncthreads();                // drain vmcnt(0): tile 0 ready

  for (int it = 0; it < ntiles; ++it) {
    const int kt0 = it * 64;
    const int cur = it & 1;
    if (it + 1 < ntiles) STAGE(cur ^ 1);   // prefetch rides under compute

    if (kt0 <= twave_hi) {
      const char* kb = (const char*)sK[cur];
      const char* vb = (const char*)sVt[cur];
      // ---- S^T = K @ Q^T ----
      f32x16 st[2] = {};
      __builtin_amdgcn_s_setprio(1);
      #pragma unroll
      for (int mt = 0; mt < 2; ++mt) {
        const int row = mt * 32 + lq;
        const int rsw = (row & 7) << 4;
        #pragma unroll
        for (int ks = 0; ks < 4; ++ks) {
          bf16x8 kf = *(const bf16x8*)(kb + row * 128 + ((ks * 32 + hi * 16) ^ rsw));
          st[mt] = __builtin_amdgcn_mfma_f32_32x32x16_bf16(kf, qf[ks], st[mt], 0, 0, 0);
        }
      }
      __builtin_amdgcn_s_setprio(0);
      // ---- causal mask ----
      if (kt0 + 63 > twave_lo) {
        #pragma unroll
        for (int mt = 0; mt < 2; ++mt)
          #pragma unroll
          for (int r = 0; r < 16; ++r) {
            int ktg = kt0 + mt * 32 + (r & 3) + 8 * (r >> 2) + 4 * hi;
            if (ktg > tq) st[mt][r] = -1e30f;
          }
      }
      // ---- online softmax (base 2, defer-max) ----
      float rm = st[0][0];
      #pragma unroll
      for (int r = 1; r < 16; ++r) rm = fmaxf(rm, st[0][r]);
      #pragma unroll
      for (int r = 0; r < 16; ++r) rm = fmaxf(rm, st[1][r]);
      rm = fmaxf(rm, __shfl_xor(rm, 32));
      if (__any(rm > m + 8.f)) {
        float mnew = fmaxf(m, rm);
        float corr = exp2f(m - mnew);
        m = mnew;
        lsum *= corr;
        #pragma unroll
        for (int r = 0; r < 16; ++r) { of[0][r] *= corr; of[1][r] *= corr; }
      }
      float ps = 0.f;
      #pragma unroll
      for (int mt = 0; mt < 2; ++mt)
        #pragma unroll
        for (int r = 0; r < 16; ++r) {
          float p = exp2f(st[mt][r] - m);
          st[mt][r] = p;
          ps += p;
        }
      ps += __shfl_xor(ps, 32);
      lsum += ps;
      // ---- P -> bf16 A/B-fragments (register-only) + O^T += V^T @ P^T ----
      #pragma unroll
      for (int ks = 0; ks < 4; ++ks) {
        const int mt = ks >> 1, ksl = ks & 1;
        union { bf16x2 h; int i; } u0, u1, u2, u3;
        u0.h[0] = (__bf16)st[mt][8 * ksl + 0]; u0.h[1] = (__bf16)st[mt][8 * ksl + 1];
        u1.h[0] = (__bf16)st[mt][8 * ksl + 2]; u1.h[1] = (__bf16)st[mt][8 * ksl + 3];
        u2.h[0] = (__bf16)st[mt][8 * ksl + 4]; u2.h[1] = (__bf16)st[mt][8 * ksl + 5];
        u3.h[0] = (__bf16)st[mt][8 * ksl + 6]; u3.h[1] = (__bf16)st[mt][8 * ksl + 7];
        int x0 = __shfl_xor(u0.i, 32);
        int x1 = __shfl_xor(u1.i, 32);
        int x2 = __shfl_xor(u2.i, 32);
        int x3 = __shfl_xor(u3.i, 32);
        union { int i[4]; bf16x8 v; } pf;
        pf.i[0] = hi ? x2 : u0.i;
        pf.i[1] = hi ? x3 : u1.i;
        pf.i[2] = hi ? u2.i : x0;
        pf.i[3] = hi ? u3.i : x1;
        __builtin_amdgcn_s_setprio(1);
        #pragma unroll
        for (int dt = 0; dt < 2; ++dt) {
          const int row = dt * 32 + lq;
          bf16x8 vf = *(const bf16x8*)(vb + row * 128 +
                        ((ks * 32 + hi * 16) ^ ((row & 7) << 4)));
          of[dt] = __builtin_amdgcn_mfma_f32_32x32x16_bf16(vf, pf.v, of[dt], 0, 0, 0);
        }
        __builtin_amdgcn_s_setprio(0);
      }
    }
    __syncthreads();              // vmcnt(0)+lgkmcnt(0): next tile staged
  }

  // ---- epilogue: transpose O^T through per-wave LDS, coalesced store ----
  const float inv = 1.f / lsum;
  char* pb = (char*)sK + wv * 4096;   // 32 q-rows x 128B, XOR-swizzled
  #pragma unroll
  for (int dt = 0; dt < 2; ++dt)
    #pragma unroll
    for (int r = 0; r < 16; ++r) {
      int d = dt * 32 + (r & 3) + 8 * (r >> 2) + 4 * hi;
      *(bf16_t*)(pb + lq * 128 + ((d * 2) ^ ((lq & 7) << 4))) =
          (bf16_t)(of[dt][r] * inv);
    }
  asm volatile("s_waitcnt lgkmcnt(0)" ::: "memory");
  __builtin_amdgcn_sched_barrier(0);
  #pragma unroll
  for (int rd = 0; rd < 4; ++rd) {
    int q = (l >> 3) + rd * 8;
    int ch = l & 7;
    bf16x8 ov = *(const bf16x8*)(pb + q * 128 + ((ch * 16) ^ ((q & 7) << 4)));
    *(bf16x8*)(out + (size_t)(qb + wv * 32 + q) * C + h * D + ch * 8) = ov;
  }
}

// ---------------------------------------------------------------------------
// Logits, k-split for occupancy: part[kz][b][n] = xl[b, kz*128:+128] @ Wout
// ---------------------------------------------------------------------------
__global__ __launch_bounds__(256) void logits_part_kernel(
    const float* __restrict__ xl, const float* __restrict__ Wout,
    float* __restrict__ part) {
  __shared__ float sx[B][128];
  const int k0 = blockIdx.y * 128;
  for (int i = threadIdx.x; i < B * 128; i += 256)
    sx[i >> 7][i & 127] = xl[(size_t)(i >> 7) * C + k0 + (i & 127)];
  __syncthreads();
  int n = blockIdx.x * 256 + threadIdx.x;
  float acc[B] = {};
  for (int k = 0; k < 128; ++k) {
    float w = Wout[(size_t)(k0 + k) * V + n];
    #pragma unroll
    for (int b = 0; b < B; ++b) acc[b] += sx[b][k] * w;
  }
  #pragma unroll
  for (int b = 0; b < B; ++b)
    part[((size_t)blockIdx.y * B + b) * V + n] = acc[b];
}

__global__ __launch_bounds__(256) void logits_red_kernel(
    const float* __restrict__ part, const float* __restrict__ bout,
    float* __restrict__ out) {
  int i = blockIdx.x * 256 + threadIdx.x;      // over B*V
  int n = i % V;
  float s = bout[n];
  #pragma unroll
  for (int kz = 0; kz < KSPL; ++kz)
    s += part[((size_t)kz * B + (i / V)) * V + n];
  out[i] = s;
}

// ---------------------------------------------------------------------------
extern "C" void kernel_launch(void* const* d_in, const int* in_sizes, int n_in,
                              void* d_out, int out_size, void* d_ws, size_t ws_size,
                              hipStream_t stream) {
  const int*   idx     = (const int*)  d_in[0];
  const float* tok_emb = (const float*)d_in[1];
  const float* pos_emb = (const float*)d_in[2];
  const float* Wq   = (const float*)d_in[3];
  const float* bq   = (const float*)d_in[4];
  const float* Wk   = (const float*)d_in[5];
  const float* bk   = (const float*)d_in[6];
  const float* Wv   = (const float*)d_in[7];
  const float* bv   = (const float*)d_in[8];
  const float* Wo   = (const float*)d_in[9];
  const float* bo   = (const float*)d_in[10];
  const float* ln1g = (const float*)d_in[11];
  const float* ln1b = (const float*)d_in[12];
  const float* W1   = (const float*)d_in[13];
  const float* b1   = (const float*)d_in[14];
  const float* W2   = (const float*)d_in[15];
  const float* b2   = (const float*)d_in[16];
  const float* ln2g = (const float*)d_in[17];
  const float* ln2b = (const float*)d_in[18];
  const float* lnfg = (const float*)d_in[19];
  const float* lnfb = (const float*)d_in[20];
  const float* Wout = (const float*)d_in[21];
  const float* bout = (const float*)d_in[22];
  float* out = (float*)d_out;

  // workspace layout
  char* p = (char*)d_ws;
  float*  x     = (float*)p;   p += (size_t)M * C * 4;        // fp32 residual
  float*  xl    = (float*)p;   p += (size_t)B * C * 4;
  float*  bqkv  = (float*)p;   p += (size_t)L * C3 * 4;
  float*  lpart = (float*)p;   p += (size_t)KSPL * B * V * 4; // logits partials
  bf16_t* hb    = (bf16_t*)p;  p += (size_t)M * C * 2;        // LN out / attn out
  bf16_t* qkv   = (bf16_t*)p;  p += (size_t)M * C3 * 2;       // fused QKV
  bf16_t* fb    = (bf16_t*)p;  p += (size_t)M * F * 2;        // FFN hidden
  bf16_t* WqkvT = (bf16_t*)p;  p += (size_t)L * C3 * C * 2;
  bf16_t* WoT   = (bf16_t*)p;  p += (size_t)L * C * C * 2;
  bf16_t* W1T   = (bf16_t*)p;  p += (size_t)L * F * C * 2;
  bf16_t* W2T   = (bf16_t*)p;  p += (size_t)L * C * F * 2;
  bf16_t* vt    = fb;   // aliased: vt (B*C*T bf16 = 16MB) used only during attn

  convw_kernel<<<dim3(C / 32, C / 32, L), 256, 0, stream>>>(Wq, WqkvT,             C, C, (size_t)C3 * C);
  convw_kernel<<<dim3(C / 32, C / 32, L), 256, 0, stream>>>(Wk, WqkvT + (size_t)C * C,     C, C, (size_t)C3 * C);
  convw_kernel<<<dim3(C / 32, C / 32, L), 256, 0, stream>>>(Wv, WqkvT + (size_t)2 * C * C, C, C, (size_t)C3 * C);
  convw_kernel<<<dim3(C / 32, C / 32, L), 256, 0, stream>>>(Wo, WoT, C, C, (size_t)C * C);
  convw_kernel<<<dim3(F / 32, C / 32, L), 256, 0, stream>>>(W1, W1T, C, F, (size_t)F * C);
  convw_kernel<<<dim3(C / 32, F / 32, L), 256, 0, stream>>>(W2, W2T, F, C, (size_t)C * F);
  packb_kernel<<<(L * C3) / 256, 256, 0, stream>>>(bq, bk, bv, bqkv);

  embed_kernel<<<(M * C) / 1024, 256, 0, stream>>>(idx, tok_emb, pos_emb, x);

  for (int l = 0; l < L; ++l) {
    const bf16_t* wqkv = WqkvT + (size_t)l * C3 * C;
    const bf16_t* wo   = WoT   + (size_t)l * C * C;
    const bf16_t* w1   = W1T   + (size_t)l * F * C;
    const bf16_t* w2   = W2T   + (size_t)l * C * F;

    ln_kernel<bf16_t><<<M, 256, 0, stream>>>(x, ln1g + l * C, ln1b + l * C, hb, 1, 0);
    gemm_bf16_kernel<bf16_t><<<dim3(M / 128, C3 / 128), 256, 0, stream>>>(
        hb, wqkv, bqkv + l * C3, nullptr, qkv, C3, C, 0);
    transpose_v_kernel<<<dim3(T / 32, C / 32, B), 256, 0, stream>>>(qkv, vt);
    attn_mfma_kernel<<<dim3(M / 128, H), 256, 0, stream>>>(qkv, vt, hb);
    gemm_bf16_kernel<float><<<dim3(M / 128, C / 128), 256, 0, stream>>>(
        hb, wo, bo + l * C, x, x, C, C, 0);
    ln_kernel<bf16_t><<<M, 256, 0, stream>>>(x, ln2g + l * C, ln2b + l * C, hb, 1, 0);
    gemm_bf16_kernel<bf16_t><<<dim3(M / 128, F / 128), 256, 0, stream>>>(
        hb, w1, b1 + l * F, nullptr, fb, F, C, 1);
    gemm_bf16_kernel<float><<<dim3(M / 128, C / 128), 256, 0, stream>>>(
        fb, w2, b2 + l * C, x, x, C, F, 0);
  }

  ln_kernel<float><<<B, 256, 0, stream>>>(x, lnfg, lnfb, xl, T, T - 1);
  logits_part_kernel<<<dim3(V / 256, KSPL), 256, 0, stream>>>(xl, Wout, lpart);
  logits_red_kernel<<<(B * V) / 256, 256, 0, stream>>>(lpart, bout, out);
}